// Round 1
// baseline (2410.221 us; speedup 1.0000x reference)
//
#include <hip/hip_runtime.h>
#include <hip/hip_bf16.h>

typedef __hip_bfloat16 bf16;

__device__ __forceinline__ float sigmoidf_(float x){ return 1.f/(1.f+__expf(-x)); }

// ---------------------------------------------------------------- K0: weight transposes
// W1t[c][e] = in_proj_w[e][c]   (192 x 768)
// W2t[d][o] = out_proj_w[o][d]  (384 x 192)
__global__ __launch_bounds__(256) void k0_transpose(const float* __restrict__ W1,
                                                    const float* __restrict__ W2,
                                                    float* __restrict__ W1t,
                                                    float* __restrict__ W2t){
  int idx = blockIdx.x*256 + threadIdx.x;
  if (idx < 192*768){
    int c = idx / 768, e = idx % 768;
    W1t[idx] = W1[e*192 + c];
  } else {
    int i2 = idx - 192*768;
    int d = i2 / 192, c = i2 % 192;
    W2t[i2] = W2[c*384 + d];
  }
}

// ---------------------------------------------------------------- K1: LayerNorm + in_proj
// block = 256 (4 waves), 32 pixels/block, 8 pixels/wave; lane j covers outputs j+64r, r=0..11
__global__ __launch_bounds__(256) void k1_ln_inproj(const float* __restrict__ x,
    const float* __restrict__ g1, const float* __restrict__ b1,
    const float* __restrict__ W1t, float* __restrict__ xv, float* __restrict__ z){
  __shared__ float xs[32][192];
  const int wave = threadIdx.x >> 6, lane = threadIdx.x & 63;
  const int pbase = blockIdx.x * 32;
  float g0 = g1[lane], ga = g1[lane+64], gb2 = g1[lane+128];
  float b0 = b1[lane], ba = b1[lane+64], bb2 = b1[lane+128];
  for (int q = 0; q < 8; ++q){
    int pl = wave*8 + q;
    const float* xp = x + (size_t)(pbase+pl)*192;
    float v0 = xp[lane], v1 = xp[lane+64], v2 = xp[lane+128];
    float s = v0+v1+v2, ss = v0*v0+v1*v1+v2*v2;
    #pragma unroll
    for (int off=32; off; off>>=1){ s += __shfl_xor(s,off); ss += __shfl_xor(ss,off); }
    float mu = s * (1.f/192.f);
    float var = ss * (1.f/192.f) - mu*mu;
    float rs = rsqrtf(var + 1e-6f);
    xs[pl][lane]     = (v0-mu)*rs*g0 + b0;
    xs[pl][lane+64]  = (v1-mu)*rs*ga + ba;
    xs[pl][lane+128] = (v2-mu)*rs*gb2 + bb2;
  }
  __syncthreads();
  float acc[12][8];
  #pragma unroll
  for (int r=0;r<12;++r)
    #pragma unroll
    for(int q=0;q<8;++q) acc[r][q]=0.f;
  const int prow = wave*8;
  for (int c=0;c<192;++c){
    float xv8[8];
    #pragma unroll
    for (int q=0;q<8;++q) xv8[q] = xs[prow+q][c];
    const float* wrow = W1t + c*768 + lane;
    #pragma unroll
    for (int r=0;r<12;++r){
      float w = wrow[r<<6];
      #pragma unroll
      for (int q=0;q<8;++q) acc[r][q] = fmaf(w, xv8[q], acc[r][q]);
    }
  }
  #pragma unroll
  for (int r=0;r<12;++r){
    int o = lane + (r<<6);
    #pragma unroll
    for (int q=0;q<8;++q){
      int p = pbase + prow + q;
      float v = acc[r][q];
      if (o < 384) xv[(size_t)p*384 + o]       = v;
      else         z [(size_t)p*384 + o - 384] = v;
    }
  }
}

// ---------------------------------------------------------------- K2: depthwise 3x3 conv + bias + SiLU
__global__ __launch_bounds__(256) void k2_conv(const float* __restrict__ xv,
    const float* __restrict__ cw, const float* __restrict__ cb, float* __restrict__ xc){
  int idx = blockIdx.x*256 + threadIdx.x;  // p*384 + d
  int d = idx % 384;
  int p = idx / 384;
  int b = p >> 12, hw = p & 4095, hi = hw >> 6, wi = hw & 63;
  float a = cb[d];
  #pragma unroll
  for (int dy=-1; dy<=1; ++dy){
    int h2 = hi + dy;
    if ((unsigned)h2 < 64u){
      #pragma unroll
      for (int dx=-1; dx<=1; ++dx){
        int w2 = wi + dx;
        if ((unsigned)w2 < 64u){
          float w = cw[d*9 + (dy+1)*3 + (dx+1)];
          float v = xv[((size_t)((b<<12) + (h2<<6) + w2))*384 + d];
          a = fmaf(w, v, a);
        }
      }
    }
  }
  xc[idx] = a * sigmoidf_(a);
}

// ---------------------------------------------------------------- K3: x_proj (44 dots of 384) + dt_proj + softplus
// thread = one (g,t); weights are wave-uniform -> scalar loads
__global__ __launch_bounds__(256) void k3_proj(const float* __restrict__ xc,
    const float* __restrict__ xpw,   // (K,44,384)
    const float* __restrict__ dtw,   // (K,384,12)
    const float* __restrict__ dtb,   // (K,384)
    float* __restrict__ bc,          // (G,L,32)  [B 0..15 | C 16..31]
    bf16* __restrict__ delta){       // (G,384,L)
  int bid = blockIdx.x;
  int g = bid >> 4;                  // 16 blocks per g
  int t = ((bid & 15) << 8) + threadIdx.x;
  int k = g & 3, b = g >> 2;
  int tt = (k >= 2) ? (4095 - t) : t;
  int ps = (k & 1) ? (((tt & 63) << 6) | (tt >> 6)) : tt;
  const float4* xp4 = (const float4*)(xc + ((size_t)(b<<12) + ps)*384);
  const float4* wp4 = (const float4*)(xpw + (size_t)k*44*384);
  float acc[44];
  #pragma unroll
  for (int c=0;c<44;++c) acc[c]=0.f;
  for (int cc=0; cc<96; ++cc){
    float4 xq = xp4[cc];
    #pragma unroll
    for (int c=0;c<44;++c){
      float4 wq = wp4[c*96 + cc];
      acc[c] = fmaf(xq.x, wq.x, acc[c]);
      acc[c] = fmaf(xq.y, wq.y, acc[c]);
      acc[c] = fmaf(xq.z, wq.z, acc[c]);
      acc[c] = fmaf(xq.w, wq.w, acc[c]);
    }
  }
  float* bcp = bc + ((size_t)g*4096 + t)*32;
  #pragma unroll
  for (int j=0;j<32;++j) bcp[j] = acc[12+j];
  const float* dw = dtw + (size_t)k*384*12;
  const float* db = dtb + (size_t)k*384;
  bf16* dp = delta + (size_t)g*384*4096 + t;
  for (int d=0; d<384; ++d){
    float pre = db[d];
    #pragma unroll
    for (int r=0;r<12;++r) pre = fmaf(dw[d*12+r], acc[r], pre);
    float dl = (pre > 20.f) ? pre : log1pf(expf(pre));
    dp[(size_t)d*4096] = __float2bfloat16(dl);
  }
}

// ---------------------------------------------------------------- K4: selective scan, n-parallel (16 lanes per (g,d) row)
__global__ __launch_bounds__(256) void k4_scan(const float* __restrict__ xc,
    const float* __restrict__ A_logs, const float* __restrict__ Ds,
    const float* __restrict__ bc, const bf16* __restrict__ delta,
    bf16* __restrict__ y4){
  const int tid = threadIdx.x;
  const int rid = blockIdx.x*16 + (tid >> 4);
  const int ln = tid & 15;
  const int g = rid / 384, d = rid % 384;
  const int k = g & 3, b = g >> 2;
  const float A = -__expf(A_logs[((size_t)(k*384+d))*16 + ln]);
  const float Dsd = Ds[k*384 + d];
  const bf16* dp = delta + ((size_t)g*384 + d)*4096;
  const float* bcg = bc + (size_t)g*4096*32;
  const float* up = xc + (size_t)(b<<12)*384 + d;
  bf16* yp = y4 + ((size_t)g*384 + d)*4096;
  float h = 0.f, ykeep = 0.f;
  for (int t16 = 0; t16 < 256; ++t16){
    #pragma unroll
    for (int j = 0; j < 16; ++j){
      int t = (t16 << 4) + j;
      int tt = (k >= 2) ? (4095 - t) : t;
      int ps = (k & 1) ? (((tt & 63) << 6) | (tt >> 6)) : tt;
      float u  = up[(size_t)ps*384];
      float dl = __bfloat162float(dp[t]);
      float Bv = bcg[t*32 + ln];
      float Cv = bcg[t*32 + 16 + ln];
      float dA = __expf(dl * A);
      float du = dl * u;
      h = fmaf(dA, h, du * Bv);
      float s = h * Cv;
      s += __shfl_xor(s, 1);
      s += __shfl_xor(s, 2);
      s += __shfl_xor(s, 4);
      s += __shfl_xor(s, 8);
      float y = fmaf(Dsd, u, s);
      ykeep = (j == ln) ? y : ykeep;
    }
    yp[(t16<<4) + ln] = __float2bfloat16(ykeep);
  }
}

// ---------------------------------------------------------------- K5: merge 4 directions -> ysum (b,d,pix)
__global__ __launch_bounds__(256) void k5_combine(const bf16* __restrict__ y4,
                                                  float* __restrict__ ysum){
  __shared__ float acc[64*65];
  const int tid = threadIdx.x;
  const int b = blockIdx.x / 384, d = blockIdx.x % 384;
  for (int i = tid; i < 64*65; i += 256) acc[i] = 0.f;
  __syncthreads();
  for (int k = 0; k < 4; ++k){
    const bf16* yp = y4 + ((size_t)(b*4+k)*384 + d)*4096;
    for (int t0 = 0; t0 < 4096; t0 += 256){
      int t = t0 + tid;
      float v = __bfloat162float(yp[t]);
      int tt = (k >= 2) ? (4095 - t) : t;
      int pix = (k & 1) ? (((tt & 63) << 6) | (tt >> 6)) : tt;
      acc[(pix >> 6)*65 + (pix & 63)] += v;
    }
    __syncthreads();
  }
  float* op = ysum + ((size_t)b*384 + d)*4096;
  for (int i = tid; i < 4096; i += 256)
    op[i] = acc[(i >> 6)*65 + (i & 63)];
}

// ---------------------------------------------------------------- K6: LN + SiLU(z) gate + out_proj + residual
// block = 256, 32-pixel tile; yt[d][p] staged in LDS (pad 33)
__global__ __launch_bounds__(256) void k6_final(const float* __restrict__ ysum,
    const float* __restrict__ z, const float* __restrict__ ong, const float* __restrict__ onb,
    const float* __restrict__ W2t, const float* __restrict__ xin, float* __restrict__ out){
  __shared__ float yt[384*33];
  __shared__ float red1[8][32], red2[8][32];
  __shared__ float mu[32], rs[32];
  const int tid = threadIdx.x;
  const int p0 = blockIdx.x * 32;
  const int b = p0 >> 12;
  const int pixbase = p0 & 4095;
  {
    int pr = tid & 31, dr0 = tid >> 5;
    for (int d = dr0; d < 384; d += 8)
      yt[d*33 + pr] = ysum[((size_t)b*384 + d)*4096 + pixbase + pr];
  }
  __syncthreads();
  {
    int p = tid & 31, q = tid >> 5;
    float s = 0.f, ss = 0.f;
    for (int i = 0; i < 48; ++i){
      float v = yt[(q*48 + i)*33 + p];
      s += v; ss += v*v;
    }
    red1[q][p] = s; red2[q][p] = ss;
  }
  __syncthreads();
  if (tid < 32){
    float s = 0.f, ss = 0.f;
    #pragma unroll
    for (int q = 0; q < 8; ++q){ s += red1[q][tid]; ss += red2[q][tid]; }
    float m = s * (1.f/384.f);
    mu[tid] = m;
    rs[tid] = rsqrtf(ss * (1.f/384.f) - m*m + 1e-5f);
  }
  __syncthreads();
  for (int i = tid; i < 384*32; i += 256){
    int d = i % 384, p = i / 384;
    float v = yt[d*33 + p];
    v = (v - mu[p]) * rs[p] * ong[d] + onb[d];
    float zv = z[(size_t)(p0 + p)*384 + d];
    yt[d*33 + p] = v * (zv * sigmoidf_(zv));
  }
  __syncthreads();
  {
    const int wave = tid >> 6, lane = tid & 63;
    float acc[3][8];
    #pragma unroll
    for (int r=0;r<3;++r)
      #pragma unroll
      for(int q=0;q<8;++q) acc[r][q]=0.f;
    for (int c = 0; c < 384; ++c){
      float w0 = W2t[c*192 + lane];
      float w1 = W2t[c*192 + lane + 64];
      float w2 = W2t[c*192 + lane + 128];
      #pragma unroll
      for (int q = 0; q < 8; ++q){
        float yv = yt[c*33 + wave*8 + q];
        acc[0][q] = fmaf(w0, yv, acc[0][q]);
        acc[1][q] = fmaf(w1, yv, acc[1][q]);
        acc[2][q] = fmaf(w2, yv, acc[2][q]);
      }
    }
    #pragma unroll
    for (int q = 0; q < 8; ++q){
      int p = p0 + wave*8 + q;
      #pragma unroll
      for (int r = 0; r < 3; ++r){
        int o = lane + (r<<6);
        out[(size_t)p*192 + o] = xin[(size_t)p*192 + o] + acc[r][q];
      }
    }
  }
}

// ---------------------------------------------------------------- launch
extern "C" void kernel_launch(void* const* d_in, const int* in_sizes, int n_in,
                              void* d_out, int out_size, void* d_ws, size_t ws_size,
                              hipStream_t stream){
  const float* x    = (const float*)d_in[0];
  const float* ln1g = (const float*)d_in[1];
  const float* ln1b = (const float*)d_in[2];
  const float* W1   = (const float*)d_in[3];
  const float* cw   = (const float*)d_in[4];
  const float* cb   = (const float*)d_in[5];
  const float* xpw  = (const float*)d_in[6];
  const float* dtw  = (const float*)d_in[7];
  const float* dtb  = (const float*)d_in[8];
  const float* alog = (const float*)d_in[9];
  const float* Dsp  = (const float*)d_in[10];
  const float* ong  = (const float*)d_in[11];
  const float* onb  = (const float*)d_in[12];
  const float* W2   = (const float*)d_in[13];
  float* out = (float*)d_out;

  char* ws = (char*)d_ws;
  size_t off = 0;
  auto alloc = [&](size_t bytes){ void* p = ws + off; off += (bytes + 255) & ~size_t(255); return p; };
  float* W1t  = (float*)alloc((size_t)192*768*4);
  float* W2t  = (float*)alloc((size_t)384*192*4);
  float* xv   = (float*)alloc((size_t)16384*384*4);  // dead after k2; reused as ysum
  float* zb   = (float*)alloc((size_t)16384*384*4);
  float* xc   = (float*)alloc((size_t)16384*384*4);
  float* bcb  = (float*)alloc((size_t)16*4096*32*4);
  bf16*  dl   = (bf16*)alloc((size_t)16*384*4096*2);
  bf16*  y4   = (bf16*)alloc((size_t)16*384*4096*2);
  float* ysum = xv;

  k0_transpose<<<864, 256, 0, stream>>>(W1, W2, W1t, W2t);
  k1_ln_inproj<<<512, 256, 0, stream>>>(x, ln1g, ln1b, W1t, xv, zb);
  k2_conv<<<24576, 256, 0, stream>>>(xv, cw, cb, xc);
  k3_proj<<<256, 256, 0, stream>>>(xc, xpw, dtw, dtb, bcb, dl);
  k4_scan<<<384, 256, 0, stream>>>(xc, alog, Dsp, bcb, dl, y4);
  k5_combine<<<1536, 256, 0, stream>>>(y4, ysum);
  k6_final<<<512, 256, 0, stream>>>(ysum, zb, ong, onb, W2t, x, out);
}

// Round 2
// 1299.720 us; speedup vs baseline: 1.8544x; 1.8544x over previous
//
#include <hip/hip_runtime.h>
#include <hip/hip_bf16.h>

typedef __hip_bfloat16 bf16;

__device__ __forceinline__ float sigmoidf_(float x){ return 1.f/(1.f+__expf(-x)); }

// ---------------------------------------------------------------- K0: weight transposes
__global__ __launch_bounds__(256) void k0_transpose(const float* __restrict__ W1,
                                                    const float* __restrict__ W2,
                                                    float* __restrict__ W1t,
                                                    float* __restrict__ W2t){
  int idx = blockIdx.x*256 + threadIdx.x;
  if (idx < 192*768){
    int c = idx / 768, e = idx % 768;
    W1t[idx] = W1[e*192 + c];
  } else {
    int i2 = idx - 192*768;
    int d = i2 / 192, c = i2 % 192;
    W2t[i2] = W2[c*384 + d];
  }
}

// ---------------------------------------------------------------- K1: LayerNorm + in_proj
__global__ __launch_bounds__(256) void k1_ln_inproj(const float* __restrict__ x,
    const float* __restrict__ g1, const float* __restrict__ b1,
    const float* __restrict__ W1t, float* __restrict__ xv, float* __restrict__ z){
  __shared__ float xs[32][192];
  const int wave = threadIdx.x >> 6, lane = threadIdx.x & 63;
  const int pbase = blockIdx.x * 32;
  float g0 = g1[lane], ga = g1[lane+64], gb2 = g1[lane+128];
  float b0 = b1[lane], ba = b1[lane+64], bb2 = b1[lane+128];
  for (int q = 0; q < 8; ++q){
    int pl = wave*8 + q;
    const float* xp = x + (size_t)(pbase+pl)*192;
    float v0 = xp[lane], v1 = xp[lane+64], v2 = xp[lane+128];
    float s = v0+v1+v2, ss = v0*v0+v1*v1+v2*v2;
    #pragma unroll
    for (int off=32; off; off>>=1){ s += __shfl_xor(s,off); ss += __shfl_xor(ss,off); }
    float mu = s * (1.f/192.f);
    float var = ss * (1.f/192.f) - mu*mu;
    float rs = rsqrtf(var + 1e-6f);
    xs[pl][lane]     = (v0-mu)*rs*g0 + b0;
    xs[pl][lane+64]  = (v1-mu)*rs*ga + ba;
    xs[pl][lane+128] = (v2-mu)*rs*gb2 + bb2;
  }
  __syncthreads();
  float acc[12][8];
  #pragma unroll
  for (int r=0;r<12;++r)
    #pragma unroll
    for(int q=0;q<8;++q) acc[r][q]=0.f;
  const int prow = wave*8;
  for (int c=0;c<192;++c){
    float xv8[8];
    #pragma unroll
    for (int q=0;q<8;++q) xv8[q] = xs[prow+q][c];
    const float* wrow = W1t + c*768 + lane;
    #pragma unroll
    for (int r=0;r<12;++r){
      float w = wrow[r<<6];
      #pragma unroll
      for (int q=0;q<8;++q) acc[r][q] = fmaf(w, xv8[q], acc[r][q]);
    }
  }
  #pragma unroll
  for (int r=0;r<12;++r){
    int o = lane + (r<<6);
    #pragma unroll
    for (int q=0;q<8;++q){
      int p = pbase + prow + q;
      float v = acc[r][q];
      if (o < 384) xv[(size_t)p*384 + o]       = v;
      else         z [(size_t)p*384 + o - 384] = v;
    }
  }
}

// ---------------------------------------------------------------- K2: depthwise 3x3 conv + bias + SiLU
__global__ __launch_bounds__(256) void k2_conv(const float* __restrict__ xv,
    const float* __restrict__ cw, const float* __restrict__ cb, float* __restrict__ xc){
  int idx = blockIdx.x*256 + threadIdx.x;  // p*384 + d
  int d = idx % 384;
  int p = idx / 384;
  int b = p >> 12, hw = p & 4095, hi = hw >> 6, wi = hw & 63;
  float a = cb[d];
  #pragma unroll
  for (int dy=-1; dy<=1; ++dy){
    int h2 = hi + dy;
    if ((unsigned)h2 < 64u){
      #pragma unroll
      for (int dx=-1; dx<=1; ++dx){
        int w2 = wi + dx;
        if ((unsigned)w2 < 64u){
          float w = cw[d*9 + (dy+1)*3 + (dx+1)];
          float v = xv[((size_t)((b<<12) + (h2<<6) + w2))*384 + d];
          a = fmaf(w, v, a);
        }
      }
    }
  }
  xc[idx] = a * sigmoidf_(a);
}

// ---------------------------------------------------------------- K3: x_proj + dt_proj + softplus
__global__ __launch_bounds__(256) void k3_proj(const float* __restrict__ xc,
    const float* __restrict__ xpw,   // (K,44,384)
    const float* __restrict__ dtw,   // (K,384,12)
    const float* __restrict__ dtb,   // (K,384)
    float* __restrict__ bc,          // (G,L,32)  [B 0..15 | C 16..31]
    bf16* __restrict__ delta){       // (G,384,L)
  int bid = blockIdx.x;
  int g = bid >> 4;
  int t = ((bid & 15) << 8) + threadIdx.x;
  int k = g & 3, b = g >> 2;
  int tt = (k >= 2) ? (4095 - t) : t;
  int ps = (k & 1) ? (((tt & 63) << 6) | (tt >> 6)) : tt;
  const float4* xp4 = (const float4*)(xc + ((size_t)(b<<12) + ps)*384);
  const float4* wp4 = (const float4*)(xpw + (size_t)k*44*384);
  float acc[44];
  #pragma unroll
  for (int c=0;c<44;++c) acc[c]=0.f;
  for (int cc=0; cc<96; ++cc){
    float4 xq = xp4[cc];
    #pragma unroll
    for (int c=0;c<44;++c){
      float4 wq = wp4[c*96 + cc];
      acc[c] = fmaf(xq.x, wq.x, acc[c]);
      acc[c] = fmaf(xq.y, wq.y, acc[c]);
      acc[c] = fmaf(xq.z, wq.z, acc[c]);
      acc[c] = fmaf(xq.w, wq.w, acc[c]);
    }
  }
  float* bcp = bc + ((size_t)g*4096 + t)*32;
  #pragma unroll
  for (int j=0;j<32;++j) bcp[j] = acc[12+j];
  const float* dw = dtw + (size_t)k*384*12;
  const float* db = dtb + (size_t)k*384;
  bf16* dp = delta + (size_t)g*384*4096 + t;
  for (int d=0; d<384; ++d){
    float pre = db[d];
    #pragma unroll
    for (int r=0;r<12;++r) pre = fmaf(dw[d*12+r], acc[r], pre);
    float dl = (pre > 20.f) ? pre : log1pf(expf(pre));
    dp[(size_t)d*4096] = __float2bfloat16(dl);
  }
}

// ---------------------------------------------------------------- K4a: chunked scan, local pass
// block: (g, ch, dgrp): 16 rows (d) x 16 lanes (n). Computes per-chunk (P, h_local).
__global__ __launch_bounds__(256) void k4a_local(const float* __restrict__ xc,
    const float* __restrict__ A_logs,
    const float* __restrict__ bc, const bf16* __restrict__ delta,
    float2* __restrict__ ph){
  const int tid = threadIdx.x;
  const int r = tid >> 4, ln = tid & 15;
  int bid = blockIdx.x;
  const int dgrp = bid % 24; bid /= 24;
  const int ch = bid & 63;
  const int g = bid >> 6;
  const int d = dgrp*16 + r;
  const int k = g & 3, b = g >> 2;
  const float A = -__expf(A_logs[((size_t)(k*384+d))*16 + ln]);
  const bf16* dp = delta + ((size_t)g*384 + d)*4096;
  const float* bcg = bc + (size_t)g*4096*32;
  const float* up = xc + (size_t)(b<<12)*384 + d;
  float h = 0.f, P = 1.f;
  const int t0 = ch << 6;
  #pragma unroll 16
  for (int j = 0; j < 64; ++j){
    int t = t0 + j;
    int tt = (k >= 2) ? (4095 - t) : t;
    int ps = (k & 1) ? (((tt & 63) << 6) | (tt >> 6)) : tt;
    float u  = up[(size_t)ps*384];
    float dl = __bfloat162float(dp[t]);
    float Bv = bcg[t*32 + ln];
    float dA = __expf(dl * A);
    h = fmaf(dA, h, dl * u * Bv);
    P *= dA;
  }
  ph[(((size_t)g*384 + d)*64 + ch)*16 + ln] = make_float2(P, h);
}

// ---------------------------------------------------------------- K4b: combine chunk summaries -> h_start per chunk
__global__ __launch_bounds__(256) void k4b_combine(const float2* __restrict__ ph,
                                                   float* __restrict__ hst){
  int gid = blockIdx.x*256 + threadIdx.x;   // (g*384+d)*16 + n
  int n = gid & 15;
  size_t base = ((size_t)(gid >> 4))*64*16 + n;
  float h = 0.f;
  #pragma unroll 8
  for (int ch = 0; ch < 64; ++ch){
    hst[base + ch*16] = h;
    float2 p = ph[base + ch*16];
    h = fmaf(p.x, h, p.y);
  }
}

// ---------------------------------------------------------------- K4c: final pass, seeded by h_start, emits y
__global__ __launch_bounds__(256) void k4c_scan(const float* __restrict__ xc,
    const float* __restrict__ A_logs, const float* __restrict__ Ds,
    const float* __restrict__ bc, const bf16* __restrict__ delta,
    const float* __restrict__ hst, bf16* __restrict__ y4){
  const int tid = threadIdx.x;
  const int r = tid >> 4, ln = tid & 15;
  int bid = blockIdx.x;
  const int dgrp = bid % 24; bid /= 24;
  const int ch = bid & 63;
  const int g = bid >> 6;
  const int d = dgrp*16 + r;
  const int k = g & 3, b = g >> 2;
  const float A = -__expf(A_logs[((size_t)(k*384+d))*16 + ln]);
  const float Dsd = Ds[k*384 + d];
  const bf16* dp = delta + ((size_t)g*384 + d)*4096;
  const float* bcg = bc + (size_t)g*4096*32;
  const float* up = xc + (size_t)(b<<12)*384 + d;
  bf16* yp = y4 + ((size_t)g*384 + d)*4096;
  float h = hst[(((size_t)g*384 + d)*64 + ch)*16 + ln];
  float ykeep = 0.f;
  const int t0 = ch << 6;
  for (int j16 = 0; j16 < 4; ++j16){
    #pragma unroll
    for (int j = 0; j < 16; ++j){
      int t = t0 + (j16 << 4) + j;
      int tt = (k >= 2) ? (4095 - t) : t;
      int ps = (k & 1) ? (((tt & 63) << 6) | (tt >> 6)) : tt;
      float u  = up[(size_t)ps*384];
      float dl = __bfloat162float(dp[t]);
      float Bv = bcg[t*32 + ln];
      float Cv = bcg[t*32 + 16 + ln];
      float dA = __expf(dl * A);
      h = fmaf(dA, h, dl * u * Bv);
      float s = h * Cv;
      s += __shfl_xor(s, 1);
      s += __shfl_xor(s, 2);
      s += __shfl_xor(s, 4);
      s += __shfl_xor(s, 8);
      float y = fmaf(Dsd, u, s);
      ykeep = (j == ln) ? y : ykeep;
    }
    yp[t0 + (j16<<4) + ln] = __float2bfloat16(ykeep);
  }
}

// ---------------------------------------------------------------- K5: merge 4 directions -> ysum (b,d,pix)
__global__ __launch_bounds__(256) void k5_combine(const bf16* __restrict__ y4,
                                                  float* __restrict__ ysum){
  __shared__ float acc[64*65];
  const int tid = threadIdx.x;
  const int b = blockIdx.x / 384, d = blockIdx.x % 384;
  for (int i = tid; i < 64*65; i += 256) acc[i] = 0.f;
  __syncthreads();
  for (int k = 0; k < 4; ++k){
    const bf16* yp = y4 + ((size_t)(b*4+k)*384 + d)*4096;
    for (int t0 = 0; t0 < 4096; t0 += 256){
      int t = t0 + tid;
      float v = __bfloat162float(yp[t]);
      int tt = (k >= 2) ? (4095 - t) : t;
      int pix = (k & 1) ? (((tt & 63) << 6) | (tt >> 6)) : tt;
      acc[(pix >> 6)*65 + (pix & 63)] += v;
    }
    __syncthreads();
  }
  float* op = ysum + ((size_t)b*384 + d)*4096;
  for (int i = tid; i < 4096; i += 256)
    op[i] = acc[(i >> 6)*65 + (i & 63)];
}

// ---------------------------------------------------------------- K6: LN + SiLU(z) gate + out_proj + residual
__global__ __launch_bounds__(256) void k6_final(const float* __restrict__ ysum,
    const float* __restrict__ z, const float* __restrict__ ong, const float* __restrict__ onb,
    const float* __restrict__ W2t, const float* __restrict__ xin, float* __restrict__ out){
  __shared__ float yt[384*33];
  __shared__ float red1[8][32], red2[8][32];
  __shared__ float mu[32], rs[32];
  const int tid = threadIdx.x;
  const int p0 = blockIdx.x * 32;
  const int b = p0 >> 12;
  const int pixbase = p0 & 4095;
  {
    int pr = tid & 31, dr0 = tid >> 5;
    for (int d = dr0; d < 384; d += 8)
      yt[d*33 + pr] = ysum[((size_t)b*384 + d)*4096 + pixbase + pr];
  }
  __syncthreads();
  {
    int p = tid & 31, q = tid >> 5;
    float s = 0.f, ss = 0.f;
    for (int i = 0; i < 48; ++i){
      float v = yt[(q*48 + i)*33 + p];
      s += v; ss += v*v;
    }
    red1[q][p] = s; red2[q][p] = ss;
  }
  __syncthreads();
  if (tid < 32){
    float s = 0.f, ss = 0.f;
    #pragma unroll
    for (int q = 0; q < 8; ++q){ s += red1[q][tid]; ss += red2[q][tid]; }
    float m = s * (1.f/384.f);
    mu[tid] = m;
    rs[tid] = rsqrtf(ss * (1.f/384.f) - m*m + 1e-5f);
  }
  __syncthreads();
  for (int i = tid; i < 384*32; i += 256){
    int d = i % 384, p = i / 384;
    float v = yt[d*33 + p];
    v = (v - mu[p]) * rs[p] * ong[d] + onb[d];
    float zv = z[(size_t)(p0 + p)*384 + d];
    yt[d*33 + p] = v * (zv * sigmoidf_(zv));
  }
  __syncthreads();
  {
    const int wave = tid >> 6, lane = tid & 63;
    float acc[3][8];
    #pragma unroll
    for (int r=0;r<3;++r)
      #pragma unroll
      for(int q=0;q<8;++q) acc[r][q]=0.f;
    for (int c = 0; c < 384; ++c){
      float w0 = W2t[c*192 + lane];
      float w1 = W2t[c*192 + lane + 64];
      float w2 = W2t[c*192 + lane + 128];
      #pragma unroll
      for (int q = 0; q < 8; ++q){
        float yv = yt[c*33 + wave*8 + q];
        acc[0][q] = fmaf(w0, yv, acc[0][q]);
        acc[1][q] = fmaf(w1, yv, acc[1][q]);
        acc[2][q] = fmaf(w2, yv, acc[2][q]);
      }
    }
    #pragma unroll
    for (int q = 0; q < 8; ++q){
      int p = p0 + wave*8 + q;
      #pragma unroll
      for (int r = 0; r < 3; ++r){
        int o = lane + (r<<6);
        out[(size_t)p*192 + o] = xin[(size_t)p*192 + o] + acc[r][q];
      }
    }
  }
}

// ---------------------------------------------------------------- launch
extern "C" void kernel_launch(void* const* d_in, const int* in_sizes, int n_in,
                              void* d_out, int out_size, void* d_ws, size_t ws_size,
                              hipStream_t stream){
  const float* x    = (const float*)d_in[0];
  const float* ln1g = (const float*)d_in[1];
  const float* ln1b = (const float*)d_in[2];
  const float* W1   = (const float*)d_in[3];
  const float* cw   = (const float*)d_in[4];
  const float* cb   = (const float*)d_in[5];
  const float* xpw  = (const float*)d_in[6];
  const float* dtw  = (const float*)d_in[7];
  const float* dtb  = (const float*)d_in[8];
  const float* alog = (const float*)d_in[9];
  const float* Dsp  = (const float*)d_in[10];
  const float* ong  = (const float*)d_in[11];
  const float* onb  = (const float*)d_in[12];
  const float* W2   = (const float*)d_in[13];
  float* out = (float*)d_out;

  char* ws = (char*)d_ws;
  size_t off = 0;
  auto alloc = [&](size_t bytes){ void* p = ws + off; off += (bytes + 255) & ~size_t(255); return p; };
  float* W1t  = (float*)alloc((size_t)192*768*4);
  float* W2t  = (float*)alloc((size_t)384*192*4);
  float* xv   = (float*)alloc((size_t)16384*384*4);  // dead after k2; reused as hst, then ysum
  float* zb   = (float*)alloc((size_t)16384*384*4);
  float* xc   = (float*)alloc((size_t)16384*384*4);
  float* bcb  = (float*)alloc((size_t)16*4096*32*4);
  bf16*  dl   = (bf16*)alloc((size_t)16*384*4096*2);
  bf16*  y4   = (bf16*)alloc((size_t)16*384*4096*2);
  // aliases (stream-serialized lifetimes):
  float2* ph  = (float2*)y4;   // written k4a, consumed k4b, then y4 overwritten by k4c
  float*  hst = xv;            // written k4b, read k4c; xv dead after k2; ysum written in k5
  float* ysum = xv;

  k0_transpose<<<864, 256, 0, stream>>>(W1, W2, W1t, W2t);
  k1_ln_inproj<<<512, 256, 0, stream>>>(x, ln1g, ln1b, W1t, xv, zb);
  k2_conv<<<24576, 256, 0, stream>>>(xv, cw, cb, xc);
  k3_proj<<<256, 256, 0, stream>>>(xc, xpw, dtw, dtb, bcb, dl);
  k4a_local<<<16*64*24, 256, 0, stream>>>(xc, alog, bcb, dl, ph);
  k4b_combine<<<384, 256, 0, stream>>>(ph, hst);
  k4c_scan<<<16*64*24, 256, 0, stream>>>(xc, alog, Dsp, bcb, dl, hst, y4);
  k5_combine<<<1536, 256, 0, stream>>>(y4, ysum);
  k6_final<<<512, 256, 0, stream>>>(ysum, zb, ong, onb, W2t, x, out);
}